// Round 1
// baseline (580.649 us; speedup 1.0000x reference)
//
#include <hip/hip_runtime.h>

typedef __attribute__((ext_vector_type(8))) short short8;
typedef __attribute__((ext_vector_type(8))) unsigned short us8;
typedef __attribute__((ext_vector_type(4))) unsigned short us4;
typedef __attribute__((ext_vector_type(4))) float f32x4;

static __device__ __forceinline__ unsigned short f2bf(float f) {
  union { float f; unsigned u; } c; c.f = f;
  unsigned r = (c.u + 0x7FFFu + ((c.u >> 16) & 1u)) >> 16;
  return (unsigned short)r;
}

// ---- weight/bias conversion: wq,wk,wv -> wcat bf16 [1536][512]; wp -> wpb bf16; biases -> bcat f32[1536]
__global__ __launch_bounds__(256) void conv_k(
    const float* __restrict__ wq, const float* __restrict__ wk,
    const float* __restrict__ wv, const float* __restrict__ wp,
    const float* __restrict__ bq, const float* __restrict__ bk,
    const float* __restrict__ bv,
    unsigned short* __restrict__ wcat, unsigned short* __restrict__ wpb,
    float* __restrict__ bcat)
{
  int gid = blockIdx.x * 256 + threadIdx.x;
  int i4 = gid * 4;
  const float* src;
  unsigned short* dst;
  if (i4 < 786432) {
    if (i4 < 262144)      src = wq + i4;
    else if (i4 < 524288) src = wk + (i4 - 262144);
    else                  src = wv + (i4 - 524288);
    dst = wcat + i4;
  } else {
    src = wp + (i4 - 786432);
    dst = wpb + (i4 - 786432);
  }
  f32x4 v = *(const f32x4*)src;
  us4 o;
  #pragma unroll
  for (int j = 0; j < 4; ++j) o[j] = f2bf(v[j]);
  *(us4*)dst = o;
  if (gid < 1536)
    bcat[gid] = gid < 512 ? bq[gid] : (gid < 1024 ? bk[gid - 512] : bv[gid - 1024]);
}

// ---- GroupNorm: x f32 [B,512,256] -> h bf16, one block per (b, group), 16ch x 256 = 4096 elems
__global__ __launch_bounds__(256) void gn_k(
    const float* __restrict__ x, const float* __restrict__ gw,
    const float* __restrict__ gb, unsigned short* __restrict__ h)
{
  const int b = blockIdx.x >> 5, g = blockIdx.x & 31;
  const size_t base = ((size_t)b * 512 + g * 16) * 256;
  const float* xp = x + base;
  const int tid = threadIdx.x;
  f32x4 vals[4];
  float s = 0.f, s2 = 0.f;
  #pragma unroll
  for (int j = 0; j < 4; ++j) {
    f32x4 v = *(const f32x4*)(xp + j * 1024 + tid * 4);
    vals[j] = v;
    s  += v[0] + v[1] + v[2] + v[3];
    s2 += v[0]*v[0] + v[1]*v[1] + v[2]*v[2] + v[3]*v[3];
  }
  #pragma unroll
  for (int o = 32; o; o >>= 1) { s += __shfl_xor(s, o); s2 += __shfl_xor(s2, o); }
  __shared__ float rs[8];
  if ((tid & 63) == 0) { rs[tid >> 6] = s; rs[4 + (tid >> 6)] = s2; }
  __syncthreads();
  s  = rs[0] + rs[1] + rs[2] + rs[3];
  s2 = rs[4] + rs[5] + rs[6] + rs[7];
  const float mean = s * (1.f / 4096.f);
  const float var  = s2 * (1.f / 4096.f) - mean * mean;
  const float rstd = rsqrtf(var + 1e-5f);
  unsigned short* hp = h + base;
  #pragma unroll
  for (int j = 0; j < 4; ++j) {
    const int c = g * 16 + j * 4 + (tid >> 6);
    const float sc = gw[c] * rstd;
    const float sh = gb[c] - mean * sc;
    f32x4 v = vals[j];
    us4 o;
    #pragma unroll
    for (int q = 0; q < 4; ++q) o[q] = f2bf(v[q] * sc + sh);
    *(us4*)(hp + j * 1024 + tid * 4) = o;
  }
}

// ---- row softmax over last axis (256), in-place fp32, scale 1/sqrt(512) folded in. 1 wave/row.
__global__ __launch_bounds__(256) void softmax_k(float* __restrict__ att) {
  const int row  = blockIdx.x * 4 + (threadIdx.x >> 6);
  const int lane = threadIdx.x & 63;
  float* p = att + (size_t)row * 256 + lane * 4;
  f32x4 v = *(const f32x4*)p;
  v *= 0.044194173824159216f;
  float m = fmaxf(fmaxf(v[0], v[1]), fmaxf(v[2], v[3]));
  #pragma unroll
  for (int o = 32; o; o >>= 1) m = fmaxf(m, __shfl_xor(m, o));
  f32x4 e;
  float s = 0.f;
  #pragma unroll
  for (int j = 0; j < 4; ++j) { e[j] = __expf(v[j] - m); s += e[j]; }
  #pragma unroll
  for (int o = 32; o; o >>= 1) s += __shfl_xor(s, o);
  e *= (1.f / s);
  *(f32x4*)p = e;
}

// ---- generic batched GEMM: D[b][m][n] = sum_k A[m][k]*B[k][n] (+bias[m]) (+resid) ; N fixed = 256
// A_T:    global A is [K][M] (row stride lda), transposed while staging into LDS
// B_NK:   global B is [N][K] (row stride K) — direct K-major copy; else B is [K][N] (row stride 256)
// B_F32:  B is fp32, converted to bf16 during staging
// Both LDS tiles are K-major; A and B fragments use the identical (laneGroup,i)->k slot formula,
// so the mfma intra-lane k-order ambiguity cancels.
template<bool A_T, bool B_NK, bool B_F32, bool OUT_F32, bool HAS_BIAS, bool HAS_RESID>
__global__ __launch_bounds__(256, 2) void gemm_k(
    const unsigned short* __restrict__ A, long long sAb, int lda,
    const void* __restrict__ Bv, long long sBb,
    void* __restrict__ Cv, long long sCb,
    const float* __restrict__ bias, const float* __restrict__ resid,
    int M, int K)
{
  __shared__ unsigned short Al[128][40];
  __shared__ unsigned short Bl[128][40];
  const int tid = threadIdx.x;
  const int bz = blockIdx.z;
  const int bm = blockIdx.x * 128;
  const int bn = blockIdx.y * 128;
  const unsigned short* Ab = A + (size_t)bz * sAb;
  const int l = tid & 63, w = tid >> 6;
  const int wr = w >> 1, wc = w & 1;
  const int lr = l & 15, lg = l >> 4;

  f32x4 acc[4][4];
  #pragma unroll
  for (int i = 0; i < 4; ++i)
    #pragma unroll
    for (int j = 0; j < 4; ++j) acc[i][j] = (f32x4){0.f, 0.f, 0.f, 0.f};

  for (int k0 = 0; k0 < K; k0 += 32) {
    // ---- stage A tile -> Al[m][k] (K-major)
    if (!A_T) {
      const int row = tid >> 1, kc = (tid & 1) * 16;
      const unsigned short* src = Ab + (size_t)(bm + row) * lda + (k0 + kc);
      us8 v0 = *(const us8*)src;
      us8 v1 = *(const us8*)(src + 8);
      *(us8*)&Al[row][kc] = v0;
      *(us8*)&Al[row][kc + 8] = v1;
    } else {
      const int krow = tid >> 3, mc0 = (tid & 7) * 8;
      #pragma unroll
      for (int j2 = 0; j2 < 2; ++j2) {
        const int mc = mc0 + 64 * j2;
        us8 v = *(const us8*)(Ab + (size_t)(k0 + krow) * lda + (bm + mc));
        #pragma unroll
        for (int j = 0; j < 8; ++j) Al[mc + j][krow] = v[j];
      }
    }
    // ---- stage B tile -> Bl[n][k] (K-major)
    if (B_NK) {
      const int nrow = tid >> 1, kc = (tid & 1) * 16;
      if (B_F32) {
        const float* src = (const float*)Bv + (size_t)bz * sBb + (size_t)(bn + nrow) * K + (k0 + kc);
        f32x4 f0 = *(const f32x4*)(src);
        f32x4 f1 = *(const f32x4*)(src + 4);
        f32x4 f2 = *(const f32x4*)(src + 8);
        f32x4 f3 = *(const f32x4*)(src + 12);
        us8 o0, o1;
        #pragma unroll
        for (int j = 0; j < 4; ++j) {
          o0[j] = f2bf(f0[j]); o0[4 + j] = f2bf(f1[j]);
          o1[j] = f2bf(f2[j]); o1[4 + j] = f2bf(f3[j]);
        }
        *(us8*)&Bl[nrow][kc] = o0;
        *(us8*)&Bl[nrow][kc + 8] = o1;
      } else {
        const unsigned short* src = (const unsigned short*)Bv + (size_t)bz * sBb + (size_t)(bn + nrow) * K + (k0 + kc);
        us8 v0 = *(const us8*)src;
        us8 v1 = *(const us8*)(src + 8);
        *(us8*)&Bl[nrow][kc] = v0;
        *(us8*)&Bl[nrow][kc + 8] = v1;
      }
    } else {
      const int krow = tid >> 3, nc0 = (tid & 7) * 8;
      #pragma unroll
      for (int j2 = 0; j2 < 2; ++j2) {
        const int nc = nc0 + 64 * j2;
        us8 v = *(const us8*)((const unsigned short*)Bv + (size_t)bz * sBb + (size_t)(k0 + krow) * 256 + (bn + nc));
        #pragma unroll
        for (int j = 0; j < 8; ++j) Bl[nc + j][krow] = v[j];
      }
    }
    __syncthreads();
    short8 af[4], bfr[4];
    #pragma unroll
    for (int mi = 0; mi < 4; ++mi) af[mi]  = *(const short8*)&Al[wr * 64 + mi * 16 + lr][lg * 8];
    #pragma unroll
    for (int ni = 0; ni < 4; ++ni) bfr[ni] = *(const short8*)&Bl[wc * 64 + ni * 16 + lr][lg * 8];
    #pragma unroll
    for (int mi = 0; mi < 4; ++mi)
      #pragma unroll
      for (int ni = 0; ni < 4; ++ni)
        acc[mi][ni] = __builtin_amdgcn_mfma_f32_16x16x32_bf16(af[mi], bfr[ni], acc[mi][ni], 0, 0, 0);
    __syncthreads();
  }
  // ---- epilogue: C/D layout (m89-verified): col = lane&15, row = (lane>>4)*4 + reg
  #pragma unroll
  for (int mi = 0; mi < 4; ++mi) {
    #pragma unroll
    for (int r = 0; r < 4; ++r) {
      const int row = bm + wr * 64 + mi * 16 + lg * 4 + r;
      const float bsv = HAS_BIAS ? bias[row] : 0.f;
      #pragma unroll
      for (int ni = 0; ni < 4; ++ni) {
        const int col = bn + wc * 64 + ni * 16 + lr;
        float vv = acc[mi][ni][r] + bsv;
        const size_t idx = (size_t)bz * sCb + (size_t)row * 256 + col;
        if (HAS_RESID) vv += resid[idx];
        if (OUT_F32) ((float*)Cv)[idx] = vv;
        else ((unsigned short*)Cv)[idx] = f2bf(vv);
      }
    }
  }
}

extern "C" void kernel_launch(void* const* d_in, const int* in_sizes, int n_in,
                              void* d_out, int out_size, void* d_ws, size_t ws_size,
                              hipStream_t stream)
{
  const float* x   = (const float*)d_in[0];
  const float* gnw = (const float*)d_in[1];
  const float* gnb = (const float*)d_in[2];
  const float* wq  = (const float*)d_in[3];
  const float* bq  = (const float*)d_in[4];
  const float* wk  = (const float*)d_in[5];
  const float* bk  = (const float*)d_in[6];
  const float* wv  = (const float*)d_in[7];
  const float* bv  = (const float*)d_in[8];
  const float* wp  = (const float*)d_in[9];
  const float* bp  = (const float*)d_in[10];
  float* out = (float*)d_out;

  char* ws = (char*)d_ws;
  unsigned short* wcat = (unsigned short*)(ws);                  // 1536x512 bf16
  unsigned short* wpb  = (unsigned short*)(ws + 1572864);        // 512x512 bf16
  float*          bcat = (float*)(ws + 2097152);                 // 1536 f32
  unsigned short* h    = (unsigned short*)(ws + 2103296);        // B*512*256 bf16 (reused as o_attn)
  unsigned short* qkv  = (unsigned short*)(ws + 69212160ull);    // B*1536*256 bf16
  float*          att  = (float*)(ws + 270538752ull);            // B*256*256 f32

  conv_k<<<1024, 256, 0, stream>>>(wq, wk, wv, wp, bq, bk, bv, wcat, wpb, bcat);
  gn_k<<<8192, 256, 0, stream>>>(x, gnw, gnb, h);
  // G1: qkv[b] = Wcat(1536x512) * h[b](512x256) + bcat
  gemm_k<false,false,false,false,true,false><<<dim3(12, 2, 256), 256, 0, stream>>>(
      wcat, 0, 512, h, 131072, qkv, 393216, bcat, nullptr, 1536, 512);
  // G2: att[b](256x256) = q[b]^T(256x512) * k[b](512x256)   (A staged transposed)
  gemm_k<true,false,false,true,false,false><<<dim3(2, 2, 256), 256, 0, stream>>>(
      qkv, 393216, 256, qkv + 131072, 393216, att, 65536, nullptr, nullptr, 256, 512);
  softmax_k<<<16384, 256, 0, stream>>>(att);
  // G3: o[b](512x256) = v[b](512x256) * att[b]^T   (att is [N][K] fp32 -> staged+converted)
  gemm_k<false,true,true,false,false,false><<<dim3(4, 2, 256), 256, 0, stream>>>(
      qkv + 262144, 393216, 256, att, 65536, h, 131072, nullptr, nullptr, 512, 256);
  // G4: out[b] = x[b] + wp(512x512) * o[b] + bp
  gemm_k<false,false,false,true,true,true><<<dim3(4, 2, 256), 256, 0, stream>>>(
      wpb, 0, 512, h, 131072, out, 131072, bp, x, 512, 512);
}

// Round 2
// 420.351 us; speedup vs baseline: 1.3813x; 1.3813x over previous
//
#include <hip/hip_runtime.h>

typedef __attribute__((ext_vector_type(8))) short short8;
typedef __attribute__((ext_vector_type(8))) unsigned short us8;
typedef __attribute__((ext_vector_type(4))) unsigned short us4;
typedef __attribute__((ext_vector_type(4))) float f32x4;

static __device__ __forceinline__ unsigned short f2bf(float f) {
  union { float f; unsigned u; } c; c.f = f;
  unsigned r = (c.u + 0x7FFFu + ((c.u >> 16) & 1u)) >> 16;
  return (unsigned short)r;
}

static __device__ __forceinline__ void gll16(const unsigned short* g, unsigned short* l) {
  __builtin_amdgcn_global_load_lds(
      (const __attribute__((address_space(1))) unsigned int*)g,
      (__attribute__((address_space(3))) unsigned int*)l, 16, 0, 0);
}

// ---- weight/bias conversion: wq,wk -> wqk bf16 [1024][512]; wv,wp -> bf16; bq,bk -> bqk f32[1024]
__global__ __launch_bounds__(256) void conv_k(
    const float* __restrict__ wq, const float* __restrict__ wk,
    const float* __restrict__ wv, const float* __restrict__ wp,
    const float* __restrict__ bq, const float* __restrict__ bk,
    unsigned short* __restrict__ wqk, unsigned short* __restrict__ wvb,
    unsigned short* __restrict__ wpb, float* __restrict__ bqk)
{
  int gid = blockIdx.x * 256 + threadIdx.x;
  int i4 = gid * 4;
  const float* src;
  unsigned short* dst;
  if (i4 < 524288) {
    src = (i4 < 262144) ? (wq + i4) : (wk + (i4 - 262144));
    dst = wqk + i4;
  } else if (i4 < 786432) {
    src = wv + (i4 - 524288);
    dst = wvb + (i4 - 524288);
  } else {
    src = wp + (i4 - 786432);
    dst = wpb + (i4 - 786432);
  }
  f32x4 v = *(const f32x4*)src;
  us4 o;
  #pragma unroll
  for (int j = 0; j < 4; ++j) o[j] = f2bf(v[j]);
  *(us4*)dst = o;
  if (gid < 1024)
    bqk[gid] = gid < 512 ? bq[gid] : bk[gid - 512];
}

// ---- GroupNorm -> hT [b][s=256][c=512] bf16. Block = (b, group-pair): 512 thr, 2 groups of 16ch.
__global__ __launch_bounds__(512) void gn_k(
    const float* __restrict__ x, const float* __restrict__ gw,
    const float* __restrict__ gb, unsigned short* __restrict__ hT)
{
  __shared__ unsigned short tile[32][256];   // [ch within pair][s]
  __shared__ float rs[2][4][2];
  const int b = blockIdx.x >> 4, gp = blockIdx.x & 15;
  const int tid = threadIdx.x;
  const int sub = tid >> 8;            // which group of the pair
  const int t = tid & 255;
  const int g = gp * 2 + sub;
  const float* xp = x + ((size_t)b * 512 + g * 16) * 256;
  f32x4 vals[4];
  float s = 0.f, s2 = 0.f;
  #pragma unroll
  for (int j = 0; j < 4; ++j) {
    f32x4 v = *(const f32x4*)(xp + j * 1024 + t * 4);
    vals[j] = v;
    s  += v[0] + v[1] + v[2] + v[3];
    s2 += v[0]*v[0] + v[1]*v[1] + v[2]*v[2] + v[3]*v[3];
  }
  #pragma unroll
  for (int o = 32; o; o >>= 1) { s += __shfl_xor(s, o); s2 += __shfl_xor(s2, o); }
  if ((t & 63) == 0) { rs[sub][t >> 6][0] = s; rs[sub][t >> 6][1] = s2; }
  __syncthreads();
  s  = rs[sub][0][0] + rs[sub][1][0] + rs[sub][2][0] + rs[sub][3][0];
  s2 = rs[sub][0][1] + rs[sub][1][1] + rs[sub][2][1] + rs[sub][3][1];
  const float mean = s * (1.f / 4096.f);
  const float var  = s2 * (1.f / 4096.f) - mean * mean;
  const float rstd = rsqrtf(var + 1e-5f);
  #pragma unroll
  for (int j = 0; j < 4; ++j) {
    const int cl = j * 4 + (t >> 6);                 // 0..15 within group
    const int c = g * 16 + cl;
    const float sc = gw[c] * rstd;
    const float sh = gb[c] - mean * sc;
    f32x4 v = vals[j];
    us4 o;
    #pragma unroll
    for (int q = 0; q < 4; ++q) o[q] = f2bf(v[q] * sc + sh);
    *(us4*)&tile[sub * 16 + cl][(t & 63) * 4] = o;
  }
  __syncthreads();
  // write out transposed: thread -> (s = tid>>1, half = tid&1) writes 16 ch = 32B
  const int srow = tid >> 1, half = tid & 1;
  us8 o0, o1;
  #pragma unroll
  for (int c = 0; c < 8; ++c) o0[c] = tile[half * 16 + c][srow];
  #pragma unroll
  for (int c = 0; c < 8; ++c) o1[c] = tile[half * 16 + 8 + c][srow];
  unsigned short* dst = hT + ((size_t)b * 256 + srow) * 512 + gp * 32 + half * 16;
  *(us8*)dst = o0;
  *(us8*)(dst + 8) = o1;
}

// ---- row softmax over 256, f32 in -> bf16 out, scale 1/sqrt(512). 1 wave/row.
__global__ __launch_bounds__(256) void softmax_k(
    const float* __restrict__ att, unsigned short* __restrict__ attb)
{
  const int row  = blockIdx.x * 4 + (threadIdx.x >> 6);
  const int lane = threadIdx.x & 63;
  const float* p = att + (size_t)row * 256 + lane * 4;
  f32x4 v = *(const f32x4*)p;
  v *= 0.044194173824159216f;
  float m = fmaxf(fmaxf(v[0], v[1]), fmaxf(v[2], v[3]));
  #pragma unroll
  for (int o = 32; o; o >>= 1) m = fmaxf(m, __shfl_xor(m, o));
  f32x4 e;
  float sum = 0.f;
  #pragma unroll
  for (int j = 0; j < 4; ++j) { e[j] = __expf(v[j] - m); sum += e[j]; }
  #pragma unroll
  for (int o = 32; o; o >>= 1) sum += __shfl_xor(sum, o);
  const float inv = 1.f / sum;
  us4 o;
  #pragma unroll
  for (int j = 0; j < 4; ++j) o[j] = f2bf(e[j] * inv);
  *(us4*)(attb + (size_t)row * 256 + lane * 4) = o;
}

// ---- uniform B^T-form batched GEMM: C[bz][m][n] = sum_k A[m][k]*B[n][k] (+bias)(+resid)
// A: [M][K] row-major (lda), B: [N][K] row-major (ldb), both bf16, staged via global_load_lds
// with both-sides XOR swizzle (u ^= (row>>1)&3) -> conflict-free ds_read_b128 fragments.
// BIAS_MODE: 0 none, 1 per-row (M), 2 per-col (N).
template<int BIAS_MODE, bool OUT_F32, bool HAS_RESID>
__global__ __launch_bounds__(256, 2) void gemm_k(
    const unsigned short* __restrict__ A, long long sAb, int lda,
    const unsigned short* __restrict__ B, long long sBb, int ldb,
    void* __restrict__ Cv, long long sCb, int ldc,
    const float* __restrict__ bias, const float* __restrict__ resid,
    int K)
{
  __shared__ unsigned short As[128 * 32];
  __shared__ unsigned short Bs[128 * 32];
  const int tid = threadIdx.x;
  const int bz = blockIdx.z;
  const int bm = blockIdx.x * 128;
  const int bn = blockIdx.y * 128;
  const int lane = tid & 63, w = tid >> 6;
  const int wr = w >> 1, wc = w & 1;
  const int lr = lane & 15, lg = lane >> 4;

  // staging geometry: wave w covers rows w*16 + (lane>>2), unit u = lane&3 (16B chunks of a 64B row)
  const int r = lane >> 2, u = lane & 3;
  const int ug = u ^ ((r >> 1) & 3);                  // swizzled global chunk
  const int row0 = w * 16 + r;                        // rows row0 and row0+64
  const unsigned short* Ag = A + (size_t)bz * sAb + (size_t)(bm + row0) * lda + ug * 8;
  const unsigned short* Bg = B + (size_t)bz * sBb + (size_t)(bn + row0) * ldb + ug * 8;
  unsigned short* Al = As + row0 * 32 + u * 8;
  unsigned short* Bl = Bs + row0 * 32 + u * 8;
  const size_t a64 = (size_t)64 * lda, b64 = (size_t)64 * ldb;

  // fragment-read swizzle (constant per lane)
  const int koff = (lg ^ ((lr >> 1) & 3)) * 8;

  f32x4 acc[4][4];
  #pragma unroll
  for (int i = 0; i < 4; ++i)
    #pragma unroll
    for (int j = 0; j < 4; ++j) acc[i][j] = (f32x4){0.f, 0.f, 0.f, 0.f};

  for (int k0 = 0; k0 < K; k0 += 32) {
    gll16(Ag + k0, Al);
    gll16(Ag + k0 + a64, Al + 64 * 32);
    gll16(Bg + k0, Bl);
    gll16(Bg + k0 + b64, Bl + 64 * 32);
    __syncthreads();
    short8 af[4], bf[4];
    #pragma unroll
    for (int mi = 0; mi < 4; ++mi)
      af[mi] = *(const short8*)&As[(wr * 64 + mi * 16 + lr) * 32 + koff];
    #pragma unroll
    for (int ni = 0; ni < 4; ++ni)
      bf[ni] = *(const short8*)&Bs[(wc * 64 + ni * 16 + lr) * 32 + koff];
    #pragma unroll
    for (int mi = 0; mi < 4; ++mi)
      #pragma unroll
      for (int ni = 0; ni < 4; ++ni)
        acc[mi][ni] = __builtin_amdgcn_mfma_f32_16x16x32_bf16(af[mi], bf[ni], acc[mi][ni], 0, 0, 0);
    __syncthreads();
  }
  // epilogue: C/D layout: col = lane&15, row = (lane>>4)*4 + reg
  #pragma unroll
  for (int mi = 0; mi < 4; ++mi) {
    #pragma unroll
    for (int rg = 0; rg < 4; ++rg) {
      const int rowc = bm + wr * 64 + mi * 16 + lg * 4 + rg;
      const float bm_v = (BIAS_MODE == 1) ? bias[rowc] : 0.f;
      #pragma unroll
      for (int ni = 0; ni < 4; ++ni) {
        const int col = bn + wc * 64 + ni * 16 + lr;
        float vv = acc[mi][ni][rg] + bm_v;
        if (BIAS_MODE == 2) vv += bias[col];
        const size_t idx = (size_t)bz * sCb + (size_t)rowc * ldc + col;
        if (HAS_RESID) vv += resid[idx];
        if (OUT_F32) ((float*)Cv)[idx] = vv;
        else ((unsigned short*)Cv)[idx] = f2bf(vv);
      }
    }
  }
}

extern "C" void kernel_launch(void* const* d_in, const int* in_sizes, int n_in,
                              void* d_out, int out_size, void* d_ws, size_t ws_size,
                              hipStream_t stream)
{
  const float* x   = (const float*)d_in[0];
  const float* gnw = (const float*)d_in[1];
  const float* gnb = (const float*)d_in[2];
  const float* wq  = (const float*)d_in[3];
  const float* bq  = (const float*)d_in[4];
  const float* wk  = (const float*)d_in[5];
  const float* bk  = (const float*)d_in[6];
  const float* wv  = (const float*)d_in[7];
  const float* bv  = (const float*)d_in[8];
  const float* wp  = (const float*)d_in[9];
  const float* bp  = (const float*)d_in[10];
  float* out = (float*)d_out;

  char* ws = (char*)d_ws;
  unsigned short* wqk  = (unsigned short*)(ws);                   // 1024x512 bf16 (1 MB)
  unsigned short* wvb  = (unsigned short*)(ws + 1048576);         // 512x512 bf16
  unsigned short* wpb  = (unsigned short*)(ws + 1572864);         // 512x512 bf16
  float*          bqk  = (float*)(ws + 2097152);                  // 1024 f32
  unsigned short* hT   = (unsigned short*)(ws + 2101248);         // B*256*512 bf16 (reused as oT)
  unsigned short* qkT  = (unsigned short*)(ws + 69210112ull);     // B*256*1024 bf16 (reused as attb)
  unsigned short* v    = (unsigned short*)(ws + 203427840ull);    // B*512*256 bf16
  float*          att  = (float*)(ws + 270536704ull);             // B*256*256 f32
  unsigned short* oT   = hT;
  unsigned short* attb = qkT;

  conv_k<<<1024, 256, 0, stream>>>(wq, wk, wv, wp, bq, bk, wqk, wvb, wpb, bqk);
  gn_k<<<4096, 512, 0, stream>>>(x, gnw, gnb, hT);
  // G1a: qkT[b][s][o] (o=0..1023) = hT[b] (256x512) x wqk^T ; bias per-col
  gemm_k<2, false, false><<<dim3(2, 8, 256), 256, 0, stream>>>(
      hT, 131072, 512, wqk, 0, 512, qkT, 262144, 1024, bqk, nullptr, 512);
  // G1b: v[b][c][s] = wvb (512x512) x hT[b]^T ; bias per-row
  gemm_k<1, false, false><<<dim3(4, 2, 256), 256, 0, stream>>>(
      wvb, 0, 512, hT, 131072, 512, v, 131072, 256, bv, nullptr, 512);
  // G2: att[b][s][t] f32 = q^T x k  (A=qkT rows, B=qkT+512 rows, lda/ldb=1024)
  gemm_k<0, true, false><<<dim3(2, 2, 256), 256, 0, stream>>>(
      qkT, 262144, 1024, qkT + 512, 262144, 1024, att, 65536, 256, nullptr, nullptr, 512);
  softmax_k<<<16384, 256, 0, stream>>>(att, attb);
  // G3: oT[b][t][c] = attb[b] (256x256) x v[b]^T (v is [N=c][K=s])
  gemm_k<0, false, false><<<dim3(2, 4, 256), 256, 0, stream>>>(
      attb, 65536, 256, v, 131072, 256, oT, 131072, 512, nullptr, nullptr, 256);
  // G4: out[b][c][s] = wpb (512x512) x oT[b]^T + bp + x
  gemm_k<1, true, true><<<dim3(4, 2, 256), 256, 0, stream>>>(
      wpb, 0, 512, oT, 131072, 512, out, 131072, 256, bp, x, 512);
}

// Round 3
// 374.458 us; speedup vs baseline: 1.5506x; 1.1226x over previous
//
#include <hip/hip_runtime.h>

typedef __attribute__((ext_vector_type(8))) short short8;
typedef __attribute__((ext_vector_type(8))) unsigned short us8;
typedef __attribute__((ext_vector_type(4))) unsigned short us4;
typedef __attribute__((ext_vector_type(4))) float f32x4;

static __device__ __forceinline__ unsigned short f2bf(float f) {
  union { float f; unsigned u; } c; c.f = f;
  unsigned r = (c.u + 0x7FFFu + ((c.u >> 16) & 1u)) >> 16;
  return (unsigned short)r;
}

static __device__ __forceinline__ void gll16(const unsigned short* g, unsigned short* l) {
  __builtin_amdgcn_global_load_lds(
      (const __attribute__((address_space(1))) unsigned int*)g,
      (__attribute__((address_space(3))) unsigned int*)l, 16, 0, 0);
}

// ---- weight/bias conversion
__global__ __launch_bounds__(256) void conv_k(
    const float* __restrict__ wq, const float* __restrict__ wk,
    const float* __restrict__ wv, const float* __restrict__ wp,
    const float* __restrict__ bq, const float* __restrict__ bk,
    unsigned short* __restrict__ wqk, unsigned short* __restrict__ wvb,
    unsigned short* __restrict__ wpb, float* __restrict__ bqk)
{
  int gid = blockIdx.x * 256 + threadIdx.x;
  int i4 = gid * 4;
  const float* src;
  unsigned short* dst;
  if (i4 < 524288) {
    src = (i4 < 262144) ? (wq + i4) : (wk + (i4 - 262144));
    dst = wqk + i4;
  } else if (i4 < 786432) {
    src = wv + (i4 - 524288);
    dst = wvb + (i4 - 524288);
  } else {
    src = wp + (i4 - 786432);
    dst = wpb + (i4 - 786432);
  }
  f32x4 v = *(const f32x4*)src;
  us4 o;
  #pragma unroll
  for (int j = 0; j < 4; ++j) o[j] = f2bf(v[j]);
  *(us4*)dst = o;
  if (gid < 1024)
    bqk[gid] = gid < 512 ? bq[gid] : bk[gid - 512];
}

// ---- GroupNorm -> hT [b][s=256][c=512] bf16
__global__ __launch_bounds__(512) void gn_k(
    const float* __restrict__ x, const float* __restrict__ gw,
    const float* __restrict__ gb, unsigned short* __restrict__ hT)
{
  __shared__ unsigned short tile[32][256];
  __shared__ float rs[2][4][2];
  const int b = blockIdx.x >> 4, gp = blockIdx.x & 15;
  const int tid = threadIdx.x;
  const int sub = tid >> 8;
  const int t = tid & 255;
  const int g = gp * 2 + sub;
  const float* xp = x + ((size_t)b * 512 + g * 16) * 256;
  f32x4 vals[4];
  float s = 0.f, s2 = 0.f;
  #pragma unroll
  for (int j = 0; j < 4; ++j) {
    f32x4 v = *(const f32x4*)(xp + j * 1024 + t * 4);
    vals[j] = v;
    s  += v[0] + v[1] + v[2] + v[3];
    s2 += v[0]*v[0] + v[1]*v[1] + v[2]*v[2] + v[3]*v[3];
  }
  #pragma unroll
  for (int o = 32; o; o >>= 1) { s += __shfl_xor(s, o); s2 += __shfl_xor(s2, o); }
  if ((t & 63) == 0) { rs[sub][t >> 6][0] = s; rs[sub][t >> 6][1] = s2; }
  __syncthreads();
  s  = rs[sub][0][0] + rs[sub][1][0] + rs[sub][2][0] + rs[sub][3][0];
  s2 = rs[sub][0][1] + rs[sub][1][1] + rs[sub][2][1] + rs[sub][3][1];
  const float mean = s * (1.f / 4096.f);
  const float var  = s2 * (1.f / 4096.f) - mean * mean;
  const float rstd = rsqrtf(var + 1e-5f);
  #pragma unroll
  for (int j = 0; j < 4; ++j) {
    const int cl = j * 4 + (t >> 6);
    const int c = g * 16 + cl;
    const float sc = gw[c] * rstd;
    const float sh = gb[c] - mean * sc;
    f32x4 v = vals[j];
    us4 o;
    #pragma unroll
    for (int q = 0; q < 4; ++q) o[q] = f2bf(v[q] * sc + sh);
    *(us4*)&tile[sub * 16 + cl][(t & 63) * 4] = o;
  }
  __syncthreads();
  const int srow = tid >> 1, half = tid & 1;
  us8 o0, o1;
  #pragma unroll
  for (int c = 0; c < 8; ++c) o0[c] = tile[half * 16 + c][srow];
  #pragma unroll
  for (int c = 0; c < 8; ++c) o1[c] = tile[half * 16 + 8 + c][srow];
  unsigned short* dst = hT + ((size_t)b * 256 + srow) * 512 + gp * 32 + half * 16;
  *(us8*)dst = o0;
  *(us8*)(dst + 8) = o1;
}

// ---- 256x256-tile pipelined B^T-form GEMM: C[bz][m][n] = sum_k A[m][k]*B[n][k]
// 512 threads = 8 waves (2M x 4N), per-wave 128x64 output. BK=32, 4-deep LDS ring,
// prefetch depth 3, counted vmcnt (8/4/0), raw s_barrier, setprio around MFMA clusters.
// SOFTMAX: fused row-softmax epilogue (requires M=N=256, single tile, bf16 out).
template<int NT, int BIAS_MODE, bool OUT_F32, bool HAS_RESID, bool SOFTMAX>
__global__ __launch_bounds__(512, 2) void gemm2_k(
    const unsigned short* __restrict__ A, long long sAb, int lda,
    const unsigned short* __restrict__ B, long long sBb, int ldb,
    void* __restrict__ Cv, long long sCb, int ldc,
    const float* __restrict__ bias, const float* __restrict__ resid)
{
  __shared__ unsigned short As[4][8192];
  __shared__ unsigned short Bs[4][8192];
  const int tid = threadIdx.x;
  const int bz = blockIdx.z;
  const int bm = blockIdx.x * 256;
  const int bn = blockIdx.y * 256;
  const int lane = tid & 63, w = tid >> 6;
  const int wr = w >> 2, wc = w & 3;
  const int lr = lane & 15, lg = lane >> 4;
  const int koff = (lg ^ ((lr >> 1) & 3)) * 8;

  // staging: chunk ids n0 = tid, n1 = tid+512 (16B chunks; 4 chunks per 32-elem row)
  const int n0 = tid, n1 = tid + 512;
  const int r0 = n0 >> 2, c0 = n0 & 3, g0 = c0 ^ ((r0 >> 1) & 3);
  const int r1 = n1 >> 2, c1 = n1 & 3, g1 = c1 ^ ((r1 >> 1) & 3);
  const unsigned short* Ag0 = A + (size_t)bz * sAb + (size_t)(bm + r0) * lda + g0 * 8;
  const unsigned short* Ag1 = A + (size_t)bz * sAb + (size_t)(bm + r1) * lda + g1 * 8;
  const unsigned short* Bg0 = B + (size_t)bz * sBb + (size_t)(bn + r0) * ldb + g0 * 8;
  const unsigned short* Bg1 = B + (size_t)bz * sBb + (size_t)(bn + r1) * ldb + g1 * 8;
  const int e0 = n0 * 8, e1 = n1 * 8;

  f32x4 acc[8][4];
  #pragma unroll
  for (int i = 0; i < 8; ++i)
    #pragma unroll
    for (int j = 0; j < 4; ++j) acc[i][j] = (f32x4){0.f, 0.f, 0.f, 0.f};

  // prologue: stage tiles 0,1,2 (12 events); wait tile0 (outstanding <= 8)
  #pragma unroll
  for (int t = 0; t < 3; ++t) {
    gll16(Ag0 + t * 32, &As[t][e0]);
    gll16(Ag1 + t * 32, &As[t][e1]);
    gll16(Bg0 + t * 32, &Bs[t][e0]);
    gll16(Bg1 + t * 32, &Bs[t][e1]);
  }
  asm volatile("s_waitcnt vmcnt(8)" ::: "memory");
  __builtin_amdgcn_s_barrier();

  #pragma unroll
  for (int t = 0; t < NT; ++t) {
    const unsigned short* At = &As[t & 3][0];
    const unsigned short* Bt = &Bs[t & 3][0];
    short8 af0[4], af1[4], bf[4];
    // ---- phase A: reads for m-half 0 + all B; stage A-chunks of tile t+3
    #pragma unroll
    for (int mi = 0; mi < 4; ++mi)
      af0[mi] = *(const short8*)(At + (wr * 128 + mi * 16 + lr) * 32 + koff);
    #pragma unroll
    for (int ni = 0; ni < 4; ++ni)
      bf[ni] = *(const short8*)(Bt + (wc * 64 + ni * 16 + lr) * 32 + koff);
    if (t + 3 < NT) {
      gll16(Ag0 + (t + 3) * 32, &As[(t + 3) & 3][e0]);
      gll16(Ag1 + (t + 3) * 32, &As[(t + 3) & 3][e1]);
    }
    __builtin_amdgcn_s_barrier();
    __builtin_amdgcn_s_setprio(1);
    #pragma unroll
    for (int mi = 0; mi < 4; ++mi)
      #pragma unroll
      for (int ni = 0; ni < 4; ++ni)
        acc[mi][ni] = __builtin_amdgcn_mfma_f32_16x16x32_bf16(af0[mi], bf[ni], acc[mi][ni], 0, 0, 0);
    __builtin_amdgcn_s_setprio(0);
    __builtin_amdgcn_s_barrier();
    // ---- phase B: reads for m-half 1; stage B-chunks of tile t+3
    #pragma unroll
    for (int mi = 0; mi < 4; ++mi)
      af1[mi] = *(const short8*)(At + (wr * 128 + 64 + mi * 16 + lr) * 32 + koff);
    if (t + 3 < NT) {
      gll16(Bg0 + (t + 3) * 32, &Bs[(t + 3) & 3][e0]);
      gll16(Bg1 + (t + 3) * 32, &Bs[(t + 3) & 3][e1]);
    }
    __builtin_amdgcn_s_barrier();
    __builtin_amdgcn_s_setprio(1);
    #pragma unroll
    for (int mi = 0; mi < 4; ++mi)
      #pragma unroll
      for (int ni = 0; ni < 4; ++ni)
        acc[4 + mi][ni] = __builtin_amdgcn_mfma_f32_16x16x32_bf16(af1[mi], bf[ni], acc[4 + mi][ni], 0, 0, 0);
    __builtin_amdgcn_s_setprio(0);
    // ---- end-of-tile counted wait: tile t+1 complete; t+2/t+3 stay in flight
    if (t < NT - 1) {
      const int left = NT - 2 - t;
      if (left >= 2)      asm volatile("s_waitcnt vmcnt(8)" ::: "memory");
      else if (left == 1) asm volatile("s_waitcnt vmcnt(4)" ::: "memory");
      else                asm volatile("s_waitcnt vmcnt(0)" ::: "memory");
      __builtin_amdgcn_s_barrier();
    }
  }

  if (SOFTMAX) {
    // fused row softmax over n (256 cols in-block); scale 1/sqrt(512); bf16 out
    const float SC = 0.044194173824159216f;
    float* redm = (float*)&As[0][0];       // [256][4]
    float* reds = redm + 1024;             // [256][4]
    float rmax[8][4];
    #pragma unroll
    for (int mi = 0; mi < 8; ++mi)
      #pragma unroll
      for (int r = 0; r < 4; ++r) {
        float m = fmaxf(fmaxf(acc[mi][0][r], acc[mi][1][r]),
                        fmaxf(acc[mi][2][r], acc[mi][3][r]));
        #pragma unroll
        for (int o = 1; o <= 8; o <<= 1) m = fmaxf(m, __shfl_xor(m, o));
        rmax[mi][r] = m;
      }
    __syncthreads();
    if (lr == 0) {
      #pragma unroll
      for (int mi = 0; mi < 8; ++mi)
        #pragma unroll
        for (int r = 0; r < 4; ++r)
          redm[(wr * 128 + mi * 16 + lg * 4 + r) * 4 + wc] = rmax[mi][r];
    }
    __syncthreads();
    float rsum[8][4];
    #pragma unroll
    for (int mi = 0; mi < 8; ++mi)
      #pragma unroll
      for (int r = 0; r < 4; ++r) {
        const int row = wr * 128 + mi * 16 + lg * 4 + r;
        f32x4 q = *(const f32x4*)&redm[row * 4];
        const float m = fmaxf(fmaxf(q[0], q[1]), fmaxf(q[2], q[3]));
        float s = 0.f;
        #pragma unroll
        for (int ni = 0; ni < 4; ++ni) {
          float e = __expf((acc[mi][ni][r] - m) * SC);
          acc[mi][ni][r] = e;
          s += e;
        }
        #pragma unroll
        for (int o = 1; o <= 8; o <<= 1) s += __shfl_xor(s, o);
        rsum[mi][r] = s;
      }
    if (lr == 0) {
      #pragma unroll
      for (int mi = 0; mi < 8; ++mi)
        #pragma unroll
        for (int r = 0; r < 4; ++r)
          reds[(wr * 128 + mi * 16 + lg * 4 + r) * 4 + wc] = rsum[mi][r];
    }
    __syncthreads();
    unsigned short* Cb = (unsigned short*)Cv + (size_t)bz * sCb;
    #pragma unroll
    for (int mi = 0; mi < 8; ++mi)
      #pragma unroll
      for (int r = 0; r < 4; ++r) {
        const int row = wr * 128 + mi * 16 + lg * 4 + r;
        f32x4 q = *(const f32x4*)&reds[row * 4];
        const float inv = 1.f / (q[0] + q[1] + q[2] + q[3]);
        #pragma unroll
        for (int ni = 0; ni < 4; ++ni) {
          const int col = wc * 64 + ni * 16 + lr;
          Cb[(size_t)row * ldc + col] = f2bf(acc[mi][ni][r] * inv);
        }
      }
  } else {
    #pragma unroll
    for (int mi = 0; mi < 8; ++mi)
      #pragma unroll
      for (int r = 0; r < 4; ++r) {
        const int rowc = bm + wr * 128 + mi * 16 + lg * 4 + r;
        const float bv_ = (BIAS_MODE == 1) ? bias[rowc] : 0.f;
        #pragma unroll
        for (int ni = 0; ni < 4; ++ni) {
          const int col = bn + wc * 64 + ni * 16 + lr;
          float vv = acc[mi][ni][r] + bv_;
          if (BIAS_MODE == 2) vv += bias[col];
          const size_t idx = (size_t)bz * sCb + (size_t)rowc * ldc + col;
          if (HAS_RESID) vv += resid[idx];
          if (OUT_F32) ((float*)Cv)[idx] = vv;
          else ((unsigned short*)Cv)[idx] = f2bf(vv);
        }
      }
  }
}

extern "C" void kernel_launch(void* const* d_in, const int* in_sizes, int n_in,
                              void* d_out, int out_size, void* d_ws, size_t ws_size,
                              hipStream_t stream)
{
  const float* x   = (const float*)d_in[0];
  const float* gnw = (const float*)d_in[1];
  const float* gnb = (const float*)d_in[2];
  const float* wq  = (const float*)d_in[3];
  const float* bq  = (const float*)d_in[4];
  const float* wk  = (const float*)d_in[5];
  const float* bk  = (const float*)d_in[6];
  const float* wv  = (const float*)d_in[7];
  const float* bv  = (const float*)d_in[8];
  const float* wp  = (const float*)d_in[9];
  const float* bp  = (const float*)d_in[10];
  float* out = (float*)d_out;

  char* ws = (char*)d_ws;
  unsigned short* wqk  = (unsigned short*)(ws);                   // 1024x512 bf16
  unsigned short* wvb  = (unsigned short*)(ws + 1048576);         // 512x512 bf16
  unsigned short* wpb  = (unsigned short*)(ws + 1572864);         // 512x512 bf16
  float*          bqk  = (float*)(ws + 2097152);                  // 1024 f32
  unsigned short* hT   = (unsigned short*)(ws + 2101248);         // B*256*512 bf16 (reused as oT)
  unsigned short* qkT  = (unsigned short*)(ws + 69210112ull);     // B*256*1024 bf16
  unsigned short* v    = (unsigned short*)(ws + 203427840ull);    // B*512*256 bf16
  unsigned short* attb = (unsigned short*)(ws + 270536704ull);    // B*256*256 bf16
  unsigned short* oT   = hT;

  conv_k<<<1024, 256, 0, stream>>>(wq, wk, wv, wp, bq, bk, wqk, wvb, wpb, bqk);
  gn_k<<<4096, 512, 0, stream>>>(x, gnw, gnb, hT);
  // G1a: qkT (flat 65536 x 1024) = hT (flat 65536x512) x wqk^T ; bias per-col
  gemm2_k<16, 2, false, false, false><<<dim3(256, 4, 1), 512, 0, stream>>>(
      hT, 0, 512, wqk, 0, 512, qkT, 0, 1024, bqk, nullptr);
  // G1b: v[b][c][s] = wvb (512x512) x hT[b]^T ; bias per-row
  gemm2_k<16, 1, false, false, false><<<dim3(2, 1, 256), 512, 0, stream>>>(
      wvb, 0, 512, hT, 131072, 512, v, 131072, 256, bv, nullptr);
  // G2+softmax: attb[b][s][t] = softmax(q^T k / sqrt(512))
  gemm2_k<16, 0, false, false, true><<<dim3(1, 1, 256), 512, 0, stream>>>(
      qkT, 262144, 1024, qkT + 512, 262144, 1024, attb, 65536, 256, nullptr, nullptr);
  // G3: oT[b][t][c] = attb[b] (256x256) x v[b]^T
  gemm2_k<8, 0, false, false, false><<<dim3(1, 2, 256), 512, 0, stream>>>(
      attb, 65536, 256, v, 131072, 256, oT, 131072, 512, nullptr, nullptr);
  // G4: out[b][c][s] = wpb (512x512) x oT[b]^T + bp + x
  gemm2_k<16, 1, true, true, false><<<dim3(2, 1, 256), 512, 0, stream>>>(
      wpb, 0, 512, oT, 131072, 512, out, 131072, 256, bp, x);
}